// Round 8
// baseline (622.364 us; speedup 1.0000x reference)
//
#include <hip/hip_runtime.h>
#include <math.h>

// Problem constants (fixed by the reference)
#define NN   100000
#define FIN  1024
#define HIDN 16
#define CCH  64
#define EE   3200000
#define BNEPS 1e-5f
#define NB   ((NN + 255) / 256)   // 391 scan blocks
#define NPART 8                   // XCD count
#define PSZ  (NN / NPART)         // 12500 nodes per partition

// ---------------------------------------------------------------------------
// k_hist: XCD-partitioned in-degree histogram (atomics stay in one XCD's L2)
// ---------------------------------------------------------------------------
__global__ __launch_bounds__(256) void k_hist(const int* __restrict__ ei,
                                              unsigned* __restrict__ deg) {
  int p = blockIdx.x & 7;
  int blk = blockIdx.x >> 3;
  int nblk = gridDim.x >> 3;
  int lo = p * PSZ, hi = lo + PSZ;
  for (int e = blk * 256 + threadIdx.x; e < EE; e += nblk * 256) {
    int d = ei[EE + e];
    if (d >= lo && d < hi) atomicAdd(&deg[d], 1u);
  }
}

// ---------------------------------------------------------------------------
// exclusive scan of deg -> rowptr (+ cur copy, + dis = rsqrt(deg+1))
// ---------------------------------------------------------------------------
__global__ __launch_bounds__(256) void k_scan_part(const unsigned* __restrict__ deg,
                                                   unsigned* __restrict__ exc,
                                                   unsigned* __restrict__ bsum) {
  __shared__ unsigned s[256];
  int t = threadIdx.x, i = blockIdx.x * 256 + t;
  unsigned v = (i < NN) ? deg[i] : 0u;
  s[t] = v;
  __syncthreads();
#pragma unroll
  for (int off = 1; off < 256; off <<= 1) {
    unsigned u = (t >= off) ? s[t - off] : 0u;
    __syncthreads();
    s[t] += u;
    __syncthreads();
  }
  if (i < NN) exc[i] = s[t] - v;
  if (t == 255) bsum[blockIdx.x] = s[255];
}

__global__ __launch_bounds__(512) void k_scan_boff(const unsigned* __restrict__ bsum,
                                                   unsigned* __restrict__ boff) {
  __shared__ unsigned s[512];
  int t = threadIdx.x;
  unsigned v = (t < NB) ? bsum[t] : 0u;
  s[t] = v;
  __syncthreads();
#pragma unroll
  for (int off = 1; off < 512; off <<= 1) {
    unsigned u = (t >= off) ? s[t - off] : 0u;
    __syncthreads();
    s[t] += u;
    __syncthreads();
  }
  if (t < NB) boff[t] = s[t] - v;
}

__global__ __launch_bounds__(256) void k_scan_final(const unsigned* __restrict__ exc,
                                                    const unsigned* __restrict__ boff,
                                                    const unsigned* __restrict__ deg,
                                                    int* __restrict__ rowptr,
                                                    int* __restrict__ cur,
                                                    float* __restrict__ dis) {
  int i = blockIdx.x * 256 + threadIdx.x;
  if (i < NN) {
    int r = (int)(boff[i >> 8] + exc[i]);
    rowptr[i] = r;
    cur[i] = r;
    dis[i] = rsqrtf((float)(deg[i] + 1u));
  } else if (i == NN) {
    rowptr[NN] = EE;
  }
}

// ---------------------------------------------------------------------------
// k_place: XCD-partitioned bucket placement (cur + perm slices L2-local)
// ---------------------------------------------------------------------------
__global__ __launch_bounds__(256) void k_place(const int* __restrict__ ei,
                                               int* __restrict__ cur,
                                               int* __restrict__ perm) {
  int p = blockIdx.x & 7;
  int blk = blockIdx.x >> 3;
  int nblk = gridDim.x >> 3;
  int lo = p * PSZ, hi = lo + PSZ;
  for (int e = blk * 256 + threadIdx.x; e < EE; e += nblk * 256) {
    int d = ei[EE + e];
    if (d >= lo && d < hi) {
      int s = ei[e];
      int slot = atomicAdd(&cur[d], 1);
      perm[slot] = s;
    }
  }
}

// ---------------------------------------------------------------------------
// k_gemm1: SPLIT-K two-pass  (k in [HALF*512, HALF*512+512))
// Round-7 lesson: 64KB LDS capped occupancy at 2 blocks/CU (8 waves) ->
// load duty-cycle too low to reach HBM BW. Staging HALF of w1 (32 KB) gives
// 5 blocks/CU = 20 waves/CU; VGPR drops to ~110 (buf 32 + acc 64) -> no
// spill (round-6 lesson). HALF 0: partial = x[:, :512]@w1[:512]; HALF 1:
// xw1s = (partial + x[:,512:]@w1[512:]) * dis.  Extra 6.4MB round-trip: noise.
// x loads nontemporal (stream-once). Butterfly transpose-reduce per pass.
// ---------------------------------------------------------------------------
#define G1_ROWS_PER_BLOCK 128   // 4 waves * 32 rows
template <int HALF>
__global__ __launch_bounds__(256, 2) void k_gemm1(const float* __restrict__ x,
                                                  const float* __restrict__ w1,
                                                  const float* __restrict__ dis,
                                                  float* __restrict__ part,
                                                  float* __restrict__ xw1s) {
  __shared__ __align__(16) float w1s[512 * 16];
  const float4* w1v = (const float4*)w1;
  for (int idx = threadIdx.x; idx < 2048; idx += 256) {
    int k = idx >> 2, qj = idx & 3;
    int pq = qj ^ ((k >> 1) & 3);               // quad swizzle -> conflict-free
    *(float4*)&w1s[(k << 4) + (pq << 2)] = w1v[HALF * 2048 + idx];
  }
  __syncthreads();

  const int lane = threadIdx.x & 63;
  const int wave = threadIdx.x >> 6;
  const int sw = (lane >> 1) & 3;
  const int wave_row0 = blockIdx.x * G1_ROWS_PER_BLOCK + wave * 32;

  for (int g = 0; g < 8; ++g) {
    int row0 = wave_row0 + g * 4;
    if (row0 >= NN) break;
    int r0 = row0;
    int r1 = min(row0 + 1, NN - 1);
    int r2 = min(row0 + 2, NN - 1);
    int r3 = min(row0 + 3, NN - 1);

    const float* p0 = x + (size_t)r0 * FIN + HALF * 512 + lane;
    const float* p1 = x + (size_t)r1 * FIN + HALF * 512 + lane;
    const float* p2 = x + (size_t)r2 * FIN + HALF * 512 + lane;
    const float* p3 = x + (size_t)r3 * FIN + HALF * 512 + lane;

    // ---- load phase: all 32 loads in flight before any dependent use ----
    float xa[8], xb[8], xc[8], xd[8];
#pragma unroll
    for (int i = 0; i < 8; ++i) {
      xa[i] = __builtin_nontemporal_load(p0 + i * 64);
      xb[i] = __builtin_nontemporal_load(p1 + i * 64);
      xc[i] = __builtin_nontemporal_load(p2 + i * 64);
      xd[i] = __builtin_nontemporal_load(p3 + i * 64);
    }

    float acc[64];
#pragma unroll
    for (int t = 0; t < 64; ++t) acc[t] = 0.0f;

    // ---- compute phase (512 K-slice) ----
#pragma unroll
    for (int i = 0; i < 8; ++i) {
      const float* wr = &w1s[(i * 64 + lane) << 4];
      float xv0 = xa[i], xv1 = xb[i], xv2 = xc[i], xv3 = xd[i];
#pragma unroll
      for (int q = 0; q < 4; ++q) {
        float4 wq = *(const float4*)(wr + ((q ^ sw) << 2));
        int b = q * 4;
        acc[b + 0]      += xv0 * wq.x;
        acc[b + 1]      += xv0 * wq.y;
        acc[b + 2]      += xv0 * wq.z;
        acc[b + 3]      += xv0 * wq.w;
        acc[16 + b + 0] += xv1 * wq.x;
        acc[16 + b + 1] += xv1 * wq.y;
        acc[16 + b + 2] += xv1 * wq.z;
        acc[16 + b + 3] += xv1 * wq.w;
        acc[32 + b + 0] += xv2 * wq.x;
        acc[32 + b + 1] += xv2 * wq.y;
        acc[32 + b + 2] += xv2 * wq.z;
        acc[32 + b + 3] += xv2 * wq.w;
        acc[48 + b + 0] += xv3 * wq.x;
        acc[48 + b + 1] += xv3 * wq.y;
        acc[48 + b + 2] += xv3 * wq.z;
        acc[48 + b + 3] += xv3 * wq.w;
      }
    }

    // butterfly transpose-reduce: lane l ends with (row l>>4, col l&15)
#pragma unroll
    for (int o = 32; o >= 1; o >>= 1) {
      bool up = (lane & o) != 0;
#pragma unroll
      for (int t = 0; t < o; ++t) {
        float send = up ? acc[t] : acc[t + o];
        float recv = __shfl_xor(send, o, 64);
        float keep = up ? acc[t + o] : acc[t];
        acc[t] = keep + recv;
      }
    }

    int grow = row0 + (lane >> 4);
    if (grow < NN) {
      int oidx = grow * HIDN + (lane & 15);
      if (HALF == 0) {
        part[oidx] = acc[0];
      } else {
        xw1s[oidx] = (part[oidx] + acc[0]) * dis[grow];
      }
    }
  }
}

// ---------------------------------------------------------------------------
// k_agg: CSR gather-reduce, ONE WAVE PER NODE, unroll-4 (16 gathers in
// flight per wave). Features pre-scaled by dis[src].
//   v = dis_i * (sum_e sfs[perm[e]] + sfs[i])
//   MODE 0: out = relu(v + b1[j]) * dis_i  (pre-scaled for next layer)
//   MODE 1: out = v
// ---------------------------------------------------------------------------
template <int MODE>
__global__ __launch_bounds__(256) void k_agg(const int* __restrict__ rowptr,
                                             const int* __restrict__ perm,
                                             const float* __restrict__ dis,
                                             const float* __restrict__ sfs,
                                             const float* __restrict__ b1,
                                             float* __restrict__ out) {
  int g = blockIdx.x * 4 + (threadIdx.x >> 6);     // node (wave id)
  if (g >= NN) return;
  int lane = threadIdx.x & 63;
  int eo = lane >> 4;                              // 0..3
  int j = lane & 15;                               // channel
  int beg = rowptr[g], end = rowptr[g + 1];
  float acc0 = 0.0f, acc1 = 0.0f, acc2 = 0.0f, acc3 = 0.0f;
  int e = beg + eo;
  for (; e + 12 < end; e += 16) {
    int s0 = perm[e];
    int s1 = perm[e + 4];
    int s2 = perm[e + 8];
    int s3 = perm[e + 12];
    acc0 += sfs[(size_t)s0 * HIDN + j];
    acc1 += sfs[(size_t)s1 * HIDN + j];
    acc2 += sfs[(size_t)s2 * HIDN + j];
    acc3 += sfs[(size_t)s3 * HIDN + j];
  }
  for (; e < end; e += 4) acc0 += sfs[(size_t)perm[e] * HIDN + j];
  float acc = (acc0 + acc1) + (acc2 + acc3);
  acc += __shfl_xor(acc, 16, 64);
  acc += __shfl_xor(acc, 32, 64);
  if (eo == 0) {
    float di = dis[g];
    float v = di * (acc + sfs[(size_t)g * HIDN + j]);
    if (MODE == 0)
      out[(size_t)g * HIDN + j] = fmaxf(v + b1[j], 0.0f) * di;
    else
      out[(size_t)g * HIDN + j] = v;
  }
}

// ---------------------------------------------------------------------------
// k_fuse2: per row (one wave): h2 = agg2@w2 + b2 -> log_softmax ->
//          * exp(weight_raw) -> @mlp_w + mlp_b -> write d_out + f64 BN stats.
// LDS-broadcast staging (avbuf/gbuf) + float2-interleaved weights.
// ---------------------------------------------------------------------------
__global__ __launch_bounds__(256) void k_fuse2(const float* __restrict__ agg2,
                                               const float* __restrict__ w2,
                                               const float* __restrict__ b2,
                                               const float* __restrict__ mlpw,
                                               const float* __restrict__ mlpb,
                                               const float* __restrict__ wraw,
                                               float* __restrict__ out,
                                               double* __restrict__ gsum,
                                               double* __restrict__ gsq) {
  __shared__ __align__(16) float2 w2p[8 * CCH];     // (w2[2k][j], w2[2k+1][j])
  __shared__ __align__(16) float2 mlpp[32 * CCH];   // (mlp[2c][j], mlp[2c+1][j])
  __shared__ __align__(16) float avbuf[4][HIDN];
  __shared__ __align__(16) float gbuf[4][CCH];
  __shared__ double reds[256];
  __shared__ double redq[256];
  for (int idx = threadIdx.x; idx < 8 * CCH; idx += 256) {
    int k2 = idx >> 6, j = idx & 63;
    w2p[idx] = make_float2(w2[(2 * k2) * CCH + j], w2[(2 * k2 + 1) * CCH + j]);
  }
  for (int idx = threadIdx.x; idx < 32 * CCH; idx += 256) {
    int c2 = idx >> 6, j = idx & 63;
    mlpp[idx] = make_float2(mlpw[(2 * c2) * CCH + j], mlpw[(2 * c2 + 1) * CCH + j]);
  }
  __syncthreads();

  const int lane = threadIdx.x & 63;
  const int wave = threadIdx.x >> 6;
  const int j = lane;
  const float b2j = b2[j];
  const float mbj = mlpb[j];
  const int gw = blockIdx.x * 4 + wave;
  const int nw = gridDim.x * 4;

  double sum = 0.0, sq = 0.0;
  for (int i = gw; i < NN; i += nw) {
    float av = agg2[(size_t)i * HIDN + (lane & 15)];
    if (lane < HIDN) avbuf[wave][lane] = av;

    float2 h2p = make_float2(0.0f, 0.0f);
#pragma unroll
    for (int k2 = 0; k2 < 8; ++k2) {
      float2 a = *(const float2*)&avbuf[wave][2 * k2];   // broadcast read
      float2 wv = w2p[k2 * CCH + j];
      h2p.x = fmaf(a.x, wv.x, h2p.x);
      h2p.y = fmaf(a.y, wv.y, h2p.y);
    }
    float h2 = h2p.x + h2p.y + b2j;

    float mx = h2;
#pragma unroll
    for (int o = 32; o >= 1; o >>= 1) mx = fmaxf(mx, __shfl_xor(mx, o, 64));
    float ex = __expf(h2 - mx);
    float se = ex;
#pragma unroll
    for (int o = 32; o >= 1; o >>= 1) se += __shfl_xor(se, o, 64);
    float lsm = h2 - mx - __logf(se);

    float gg = __expf(wraw[i]) * lsm;
    gbuf[wave][j] = gg;

    float2 mp = make_float2(0.0f, 0.0f);
#pragma unroll
    for (int c2 = 0; c2 < 32; ++c2) {
      float2 gv = *(const float2*)&gbuf[wave][2 * c2];   // broadcast read
      float2 wv = mlpp[c2 * CCH + j];
      mp.x = fmaf(gv.x, wv.x, mp.x);
      mp.y = fmaf(gv.y, wv.y, mp.y);
    }
    float m = mp.x + mp.y + mbj;

    out[(size_t)i * CCH + j] = m;
    sum += (double)m;
    sq = fma((double)m, (double)m, sq);
  }

  reds[threadIdx.x] = sum;
  redq[threadIdx.x] = sq;
  __syncthreads();
  if (threadIdx.x < 64) {
    double s = reds[threadIdx.x] + reds[threadIdx.x + 64] +
               reds[threadIdx.x + 128] + reds[threadIdx.x + 192];
    double q = redq[threadIdx.x] + redq[threadIdx.x + 64] +
               redq[threadIdx.x + 128] + redq[threadIdx.x + 192];
    atomicAdd(&gsum[threadIdx.x], s);
    atomicAdd(&gsq[threadIdx.x], q);
  }
}

// ---------------------------------------------------------------------------
// k_stats: finalize BN params in double (no cancellation)
// ---------------------------------------------------------------------------
__global__ void k_stats(const double* __restrict__ gsum,
                        const double* __restrict__ gsq,
                        const float* __restrict__ gamma,
                        const float* __restrict__ beta,
                        float* __restrict__ bnp) {
  int j = threadIdx.x;
  if (j >= CCH) return;
  const double inv_n = 1.0 / (double)NN;
  double mean = gsum[j] * inv_n;
  double var = gsq[j] * inv_n - mean * mean;
  float sc = (float)(rsqrt(var + (double)BNEPS)) * gamma[j];
  bnp[j] = (float)mean;
  bnp[CCH + j] = sc;
  bnp[2 * CCH + j] = beta[j];
}

// ---------------------------------------------------------------------------
// k_out: BN apply + final log_softmax, in-place on d_out (wave per row)
// ---------------------------------------------------------------------------
__global__ __launch_bounds__(256) void k_out(float* __restrict__ out,
                                             const float* __restrict__ bnp) {
  const int lane = threadIdx.x & 63;
  const int wave = threadIdx.x >> 6;
  const int j = lane;
  const float mean = bnp[j];
  const float sc = bnp[CCH + j];
  const float bt = bnp[2 * CCH + j];
  const int gw = blockIdx.x * 4 + wave;
  const int nw = gridDim.x * 4;
  for (int i = gw; i < NN; i += nw) {
    float m = out[(size_t)i * CCH + j];
    float y = fmaf(m - mean, sc, bt);
    float mx = y;
#pragma unroll
    for (int o = 32; o >= 1; o >>= 1) mx = fmaxf(mx, __shfl_xor(mx, o, 64));
    float ex = __expf(y - mx);
    float se = ex;
#pragma unroll
    for (int o = 32; o >= 1; o >>= 1) se += __shfl_xor(se, o, 64);
    out[(size_t)i * CCH + j] = y - mx - __logf(se);
  }
}

// ---------------------------------------------------------------------------
extern "C" void kernel_launch(void* const* d_in, const int* in_sizes, int n_in,
                              void* d_out, int out_size, void* d_ws, size_t ws_size,
                              hipStream_t stream) {
  const float* x     = (const float*)d_in[0];
  const int*   ei    = (const int*)d_in[1];
  const float* w1    = (const float*)d_in[2];
  const float* b1    = (const float*)d_in[3];
  const float* w2    = (const float*)d_in[4];
  const float* b2    = (const float*)d_in[5];
  const float* mlpw  = (const float*)d_in[6];
  const float* mlpb  = (const float*)d_in[7];
  const float* gamma = (const float*)d_in[8];
  const float* beta  = (const float*)d_in[9];
  const float* wraw  = (const float*)d_in[10];
  float* out = (float*)d_out;

  // workspace carve (256B aligned slots)
  char* w = (char*)d_ws;
  size_t off = 0;
  auto take = [&](size_t bytes) -> void* {
    void* p = w + off;
    off = (off + bytes + 255) & ~(size_t)255;
    return p;
  };
  unsigned* deg    = (unsigned*)take((size_t)NN * 4);
  float*    dis    = (float*)take((size_t)NN * 4);
  unsigned* exc    = (unsigned*)take((size_t)NN * 4);
  unsigned* bsum   = (unsigned*)take((size_t)NB * 4);
  unsigned* boff   = (unsigned*)take((size_t)NB * 4);
  int*      rowptr = (int*)take((size_t)(NN + 1) * 4);
  int*      cur    = (int*)take((size_t)NN * 4);
  int*      perm   = (int*)take((size_t)EE * 4);
  float*    partb  = (float*)take((size_t)NN * HIDN * 4);
  float*    xw1s   = (float*)take((size_t)NN * HIDN * 4);
  float*    rh1s   = (float*)take((size_t)NN * HIDN * 4);
  float*    agg2   = (float*)take((size_t)NN * HIDN * 4);
  double*   gsum   = (double*)take(CCH * 8);
  double*   gsq    = (double*)take(CCH * 8);
  float*    bnp    = (float*)take(3 * CCH * 4);
  (void)ws_size; (void)n_in; (void)in_sizes; (void)out_size;

  hipMemsetAsync(deg, 0, (size_t)NN * 4, stream);
  hipMemsetAsync(gsum, 0, CCH * 8, stream);
  hipMemsetAsync(gsq, 0, CCH * 8, stream);

  // CSR build: XCD-partitioned histogram -> scan -> XCD-partitioned place
  k_hist<<<2048, 256, 0, stream>>>(ei, deg);
  k_scan_part<<<NB, 256, 0, stream>>>(deg, exc, bsum);
  k_scan_boff<<<1, 512, 0, stream>>>(bsum, boff);
  k_scan_final<<<(NN + 256) / 256 + 1, 256, 0, stream>>>(exc, boff, deg, rowptr, cur, dis);
  k_place<<<2048, 256, 0, stream>>>(ei, cur, perm);

  // dense transform: split-K two-pass (32KB LDS -> 5 blocks/CU each)
  const int g1grid = (NN + G1_ROWS_PER_BLOCK - 1) / G1_ROWS_PER_BLOCK;
  k_gemm1<0><<<g1grid, 256, 0, stream>>>(x, w1, dis, partb, xw1s);
  k_gemm1<1><<<g1grid, 256, 0, stream>>>(x, w1, dis, partb, xw1s);

  // 2 aggregation passes + streaming tail
  k_agg<0><<<(NN + 3) / 4, 256, 0, stream>>>(rowptr, perm, dis, xw1s, b1, rh1s);
  k_agg<1><<<(NN + 3) / 4, 256, 0, stream>>>(rowptr, perm, dis, rh1s, b1, agg2);
  k_fuse2<<<4096, 256, 0, stream>>>(agg2, w2, b2, mlpw, mlpb, wraw, out, gsum, gsq);
  k_stats<<<1, 64, 0, stream>>>(gsum, gsq, gamma, beta, bnp);
  k_out<<<2048, 256, 0, stream>>>(out, bnp);
}

// Round 9
// 619.576 us; speedup vs baseline: 1.0045x; 1.0045x over previous
//
#include <hip/hip_runtime.h>
#include <math.h>

// Problem constants (fixed by the reference)
#define NN   100000
#define FIN  1024
#define HIDN 16
#define CCH  64
#define EE   3200000
#define BNEPS 1e-5f
#define NB   ((NN + 255) / 256)   // 391 scan blocks
#define NPART 8                   // XCD count
#define PSZ  (NN / NPART)         // 12500 nodes per partition

// ---------------------------------------------------------------------------
// k_hist: XCD-partitioned in-degree histogram (atomics stay in one XCD's L2)
// ---------------------------------------------------------------------------
__global__ __launch_bounds__(256) void k_hist(const int* __restrict__ ei,
                                              unsigned* __restrict__ deg) {
  int p = blockIdx.x & 7;
  int blk = blockIdx.x >> 3;
  int nblk = gridDim.x >> 3;
  int lo = p * PSZ, hi = lo + PSZ;
  for (int e = blk * 256 + threadIdx.x; e < EE; e += nblk * 256) {
    int d = ei[EE + e];
    if (d >= lo && d < hi) atomicAdd(&deg[d], 1u);
  }
}

// ---------------------------------------------------------------------------
// exclusive scan of deg -> rowptr (+ cur copy, + dis = rsqrt(deg+1))
// ---------------------------------------------------------------------------
__global__ __launch_bounds__(256) void k_scan_part(const unsigned* __restrict__ deg,
                                                   unsigned* __restrict__ exc,
                                                   unsigned* __restrict__ bsum) {
  __shared__ unsigned s[256];
  int t = threadIdx.x, i = blockIdx.x * 256 + t;
  unsigned v = (i < NN) ? deg[i] : 0u;
  s[t] = v;
  __syncthreads();
#pragma unroll
  for (int off = 1; off < 256; off <<= 1) {
    unsigned u = (t >= off) ? s[t - off] : 0u;
    __syncthreads();
    s[t] += u;
    __syncthreads();
  }
  if (i < NN) exc[i] = s[t] - v;
  if (t == 255) bsum[blockIdx.x] = s[255];
}

__global__ __launch_bounds__(512) void k_scan_boff(const unsigned* __restrict__ bsum,
                                                   unsigned* __restrict__ boff) {
  __shared__ unsigned s[512];
  int t = threadIdx.x;
  unsigned v = (t < NB) ? bsum[t] : 0u;
  s[t] = v;
  __syncthreads();
#pragma unroll
  for (int off = 1; off < 512; off <<= 1) {
    unsigned u = (t >= off) ? s[t - off] : 0u;
    __syncthreads();
    s[t] += u;
    __syncthreads();
  }
  if (t < NB) boff[t] = s[t] - v;
}

__global__ __launch_bounds__(256) void k_scan_final(const unsigned* __restrict__ exc,
                                                    const unsigned* __restrict__ boff,
                                                    const unsigned* __restrict__ deg,
                                                    int* __restrict__ rowptr,
                                                    int* __restrict__ cur,
                                                    float* __restrict__ dis) {
  int i = blockIdx.x * 256 + threadIdx.x;
  if (i < NN) {
    int r = (int)(boff[i >> 8] + exc[i]);
    rowptr[i] = r;
    cur[i] = r;
    dis[i] = rsqrtf((float)(deg[i] + 1u));
  } else if (i == NN) {
    rowptr[NN] = EE;
  }
}

// ---------------------------------------------------------------------------
// k_place: XCD-partitioned bucket placement (cur + perm slices L2-local)
// ---------------------------------------------------------------------------
__global__ __launch_bounds__(256) void k_place(const int* __restrict__ ei,
                                               int* __restrict__ cur,
                                               int* __restrict__ perm) {
  int p = blockIdx.x & 7;
  int blk = blockIdx.x >> 3;
  int nblk = gridDim.x >> 3;
  int lo = p * PSZ, hi = lo + PSZ;
  for (int e = blk * 256 + threadIdx.x; e < EE; e += nblk * 256) {
    int d = ei[EE + e];
    if (d >= lo && d < hi) {
      int s = ei[e];
      int slot = atomicAdd(&cur[d], 1);
      perm[slot] = s;
    }
  }
}

// ---------------------------------------------------------------------------
// k_gemm1: xw1s[N,16] = (x[N,1024] @ w1[1024,16]) * dis_i  (pre-scaled)
// Round-8 lesson: split-K regressed (grid is only ~3 blocks/CU by dispatch;
// occupancy wasn't binding). Real culprit found via SQ_LDS_BANK_CONFLICT=6.4M:
// the quad swizzle had only 3 bits of entropy -> lanes 8 apart hit the same
// bank = 8-way conflict on every ds_read_b128. FIX: pad-17 row layout
// (w1s[k*17+j], 68KB, still 2 blocks/CU) + scalar b32 reads: bank =
// (17*lane+j)%32 -> only 2-way aliasing (free). Pad also blocks b128
// re-vectorization (17k never 16B-aligned). x loads nontemporal.
// ---------------------------------------------------------------------------
#define G1_ROWS_PER_BLOCK 128   // 4 waves * 32 rows
#define W1LD 17                 // padded leading dim
__global__ __launch_bounds__(256, 2) void k_gemm1(const float* __restrict__ x,
                                                  const float* __restrict__ w1,
                                                  const float* __restrict__ dis,
                                                  float* __restrict__ xw1s) {
  __shared__ float w1s[1024 * W1LD];   // 69632 B
  for (int idx = threadIdx.x; idx < 1024 * 16; idx += 256) {
    int k = idx >> 4, j = idx & 15;
    w1s[k * W1LD + j] = w1[idx];
  }
  __syncthreads();

  const int lane = threadIdx.x & 63;
  const int wave = threadIdx.x >> 6;
  const int wave_row0 = blockIdx.x * G1_ROWS_PER_BLOCK + wave * 32;

  for (int g = 0; g < 8; ++g) {
    int row0 = wave_row0 + g * 4;
    if (row0 >= NN) break;
    int r0 = row0;
    int r1 = min(row0 + 1, NN - 1);
    int r2 = min(row0 + 2, NN - 1);
    int r3 = min(row0 + 3, NN - 1);

    const float* p0 = x + (size_t)r0 * FIN + lane;
    const float* p1 = x + (size_t)r1 * FIN + lane;
    const float* p2 = x + (size_t)r2 * FIN + lane;
    const float* p3 = x + (size_t)r3 * FIN + lane;

    // ---- load phase: all 64 loads in flight before any dependent use ----
    float xa[16], xb[16], xc[16], xd[16];
#pragma unroll
    for (int i = 0; i < 16; ++i) {
      xa[i] = __builtin_nontemporal_load(p0 + i * 64);
      xb[i] = __builtin_nontemporal_load(p1 + i * 64);
      xc[i] = __builtin_nontemporal_load(p2 + i * 64);
      xd[i] = __builtin_nontemporal_load(p3 + i * 64);
    }

    float acc[64];
#pragma unroll
    for (int t = 0; t < 64; ++t) acc[t] = 0.0f;

    // ---- compute phase: b32 LDS reads, 2-way bank aliasing only ----
#pragma unroll
    for (int i = 0; i < 16; ++i) {
      const float* wr = &w1s[(i * 64 + lane) * W1LD];
      float xv0 = xa[i], xv1 = xb[i], xv2 = xc[i], xv3 = xd[i];
#pragma unroll
      for (int j = 0; j < 16; ++j) {
        float wv = wr[j];
        acc[j]      += xv0 * wv;
        acc[16 + j] += xv1 * wv;
        acc[32 + j] += xv2 * wv;
        acc[48 + j] += xv3 * wv;
      }
    }

    // butterfly transpose-reduce: lane l ends with (row l>>4, col l&15)
#pragma unroll
    for (int o = 32; o >= 1; o >>= 1) {
      bool up = (lane & o) != 0;
#pragma unroll
      for (int t = 0; t < o; ++t) {
        float send = up ? acc[t] : acc[t + o];
        float recv = __shfl_xor(send, o, 64);
        float keep = up ? acc[t + o] : acc[t];
        acc[t] = keep + recv;
      }
    }

    int grow = row0 + (lane >> 4);
    if (grow < NN) xw1s[grow * HIDN + (lane & 15)] = acc[0] * dis[grow];
  }
}

// ---------------------------------------------------------------------------
// k_agg: CSR gather-reduce, ONE WAVE PER NODE, unroll-4 (16 gathers in
// flight per wave). Features pre-scaled by dis[src].
//   v = dis_i * (sum_e sfs[perm[e]] + sfs[i])
//   MODE 0: out = relu(v + b1[j]) * dis_i  (pre-scaled for next layer)
//   MODE 1: out = v
// ---------------------------------------------------------------------------
template <int MODE>
__global__ __launch_bounds__(256) void k_agg(const int* __restrict__ rowptr,
                                             const int* __restrict__ perm,
                                             const float* __restrict__ dis,
                                             const float* __restrict__ sfs,
                                             const float* __restrict__ b1,
                                             float* __restrict__ out) {
  int g = blockIdx.x * 4 + (threadIdx.x >> 6);     // node (wave id)
  if (g >= NN) return;
  int lane = threadIdx.x & 63;
  int eo = lane >> 4;                              // 0..3
  int j = lane & 15;                               // channel
  int beg = rowptr[g], end = rowptr[g + 1];
  float acc0 = 0.0f, acc1 = 0.0f, acc2 = 0.0f, acc3 = 0.0f;
  int e = beg + eo;
  for (; e + 12 < end; e += 16) {
    int s0 = perm[e];
    int s1 = perm[e + 4];
    int s2 = perm[e + 8];
    int s3 = perm[e + 12];
    acc0 += sfs[(size_t)s0 * HIDN + j];
    acc1 += sfs[(size_t)s1 * HIDN + j];
    acc2 += sfs[(size_t)s2 * HIDN + j];
    acc3 += sfs[(size_t)s3 * HIDN + j];
  }
  for (; e < end; e += 4) acc0 += sfs[(size_t)perm[e] * HIDN + j];
  float acc = (acc0 + acc1) + (acc2 + acc3);
  acc += __shfl_xor(acc, 16, 64);
  acc += __shfl_xor(acc, 32, 64);
  if (eo == 0) {
    float di = dis[g];
    float v = di * (acc + sfs[(size_t)g * HIDN + j]);
    if (MODE == 0)
      out[(size_t)g * HIDN + j] = fmaxf(v + b1[j], 0.0f) * di;
    else
      out[(size_t)g * HIDN + j] = v;
  }
}

// ---------------------------------------------------------------------------
// k_fuse2: per row (one wave): h2 = agg2@w2 + b2 -> log_softmax ->
//          * exp(weight_raw) -> @mlp_w + mlp_b -> write d_out + f64 BN stats.
// LDS-broadcast staging (avbuf/gbuf) + float2-interleaved weights.
// ---------------------------------------------------------------------------
__global__ __launch_bounds__(256) void k_fuse2(const float* __restrict__ agg2,
                                               const float* __restrict__ w2,
                                               const float* __restrict__ b2,
                                               const float* __restrict__ mlpw,
                                               const float* __restrict__ mlpb,
                                               const float* __restrict__ wraw,
                                               float* __restrict__ out,
                                               double* __restrict__ gsum,
                                               double* __restrict__ gsq) {
  __shared__ __align__(16) float2 w2p[8 * CCH];     // (w2[2k][j], w2[2k+1][j])
  __shared__ __align__(16) float2 mlpp[32 * CCH];   // (mlp[2c][j], mlp[2c+1][j])
  __shared__ __align__(16) float avbuf[4][HIDN];
  __shared__ __align__(16) float gbuf[4][CCH];
  __shared__ double reds[256];
  __shared__ double redq[256];
  for (int idx = threadIdx.x; idx < 8 * CCH; idx += 256) {
    int k2 = idx >> 6, j = idx & 63;
    w2p[idx] = make_float2(w2[(2 * k2) * CCH + j], w2[(2 * k2 + 1) * CCH + j]);
  }
  for (int idx = threadIdx.x; idx < 32 * CCH; idx += 256) {
    int c2 = idx >> 6, j = idx & 63;
    mlpp[idx] = make_float2(mlpw[(2 * c2) * CCH + j], mlpw[(2 * c2 + 1) * CCH + j]);
  }
  __syncthreads();

  const int lane = threadIdx.x & 63;
  const int wave = threadIdx.x >> 6;
  const int j = lane;
  const float b2j = b2[j];
  const float mbj = mlpb[j];
  const int gw = blockIdx.x * 4 + wave;
  const int nw = gridDim.x * 4;

  double sum = 0.0, sq = 0.0;
  for (int i = gw; i < NN; i += nw) {
    float av = agg2[(size_t)i * HIDN + (lane & 15)];
    if (lane < HIDN) avbuf[wave][lane] = av;

    float2 h2p = make_float2(0.0f, 0.0f);
#pragma unroll
    for (int k2 = 0; k2 < 8; ++k2) {
      float2 a = *(const float2*)&avbuf[wave][2 * k2];   // broadcast read
      float2 wv = w2p[k2 * CCH + j];
      h2p.x = fmaf(a.x, wv.x, h2p.x);
      h2p.y = fmaf(a.y, wv.y, h2p.y);
    }
    float h2 = h2p.x + h2p.y + b2j;

    float mx = h2;
#pragma unroll
    for (int o = 32; o >= 1; o >>= 1) mx = fmaxf(mx, __shfl_xor(mx, o, 64));
    float ex = __expf(h2 - mx);
    float se = ex;
#pragma unroll
    for (int o = 32; o >= 1; o >>= 1) se += __shfl_xor(se, o, 64);
    float lsm = h2 - mx - __logf(se);

    float gg = __expf(wraw[i]) * lsm;
    gbuf[wave][j] = gg;

    float2 mp = make_float2(0.0f, 0.0f);
#pragma unroll
    for (int c2 = 0; c2 < 32; ++c2) {
      float2 gv = *(const float2*)&gbuf[wave][2 * c2];   // broadcast read
      float2 wv = mlpp[c2 * CCH + j];
      mp.x = fmaf(gv.x, wv.x, mp.x);
      mp.y = fmaf(gv.y, wv.y, mp.y);
    }
    float m = mp.x + mp.y + mbj;

    out[(size_t)i * CCH + j] = m;
    sum += (double)m;
    sq = fma((double)m, (double)m, sq);
  }

  reds[threadIdx.x] = sum;
  redq[threadIdx.x] = sq;
  __syncthreads();
  if (threadIdx.x < 64) {
    double s = reds[threadIdx.x] + reds[threadIdx.x + 64] +
               reds[threadIdx.x + 128] + reds[threadIdx.x + 192];
    double q = redq[threadIdx.x] + redq[threadIdx.x + 64] +
               redq[threadIdx.x + 128] + redq[threadIdx.x + 192];
    atomicAdd(&gsum[threadIdx.x], s);
    atomicAdd(&gsq[threadIdx.x], q);
  }
}

// ---------------------------------------------------------------------------
// k_stats: finalize BN params in double (no cancellation)
// ---------------------------------------------------------------------------
__global__ void k_stats(const double* __restrict__ gsum,
                        const double* __restrict__ gsq,
                        const float* __restrict__ gamma,
                        const float* __restrict__ beta,
                        float* __restrict__ bnp) {
  int j = threadIdx.x;
  if (j >= CCH) return;
  const double inv_n = 1.0 / (double)NN;
  double mean = gsum[j] * inv_n;
  double var = gsq[j] * inv_n - mean * mean;
  float sc = (float)(rsqrt(var + (double)BNEPS)) * gamma[j];
  bnp[j] = (float)mean;
  bnp[CCH + j] = sc;
  bnp[2 * CCH + j] = beta[j];
}

// ---------------------------------------------------------------------------
// k_out: BN apply + final log_softmax, in-place on d_out (wave per row)
// ---------------------------------------------------------------------------
__global__ __launch_bounds__(256) void k_out(float* __restrict__ out,
                                             const float* __restrict__ bnp) {
  const int lane = threadIdx.x & 63;
  const int wave = threadIdx.x >> 6;
  const int j = lane;
  const float mean = bnp[j];
  const float sc = bnp[CCH + j];
  const float bt = bnp[2 * CCH + j];
  const int gw = blockIdx.x * 4 + wave;
  const int nw = gridDim.x * 4;
  for (int i = gw; i < NN; i += nw) {
    float m = out[(size_t)i * CCH + j];
    float y = fmaf(m - mean, sc, bt);
    float mx = y;
#pragma unroll
    for (int o = 32; o >= 1; o >>= 1) mx = fmaxf(mx, __shfl_xor(mx, o, 64));
    float ex = __expf(y - mx);
    float se = ex;
#pragma unroll
    for (int o = 32; o >= 1; o >>= 1) se += __shfl_xor(se, o, 64);
    out[(size_t)i * CCH + j] = y - mx - __logf(se);
  }
}

// ---------------------------------------------------------------------------
extern "C" void kernel_launch(void* const* d_in, const int* in_sizes, int n_in,
                              void* d_out, int out_size, void* d_ws, size_t ws_size,
                              hipStream_t stream) {
  const float* x     = (const float*)d_in[0];
  const int*   ei    = (const int*)d_in[1];
  const float* w1    = (const float*)d_in[2];
  const float* b1    = (const float*)d_in[3];
  const float* w2    = (const float*)d_in[4];
  const float* b2    = (const float*)d_in[5];
  const float* mlpw  = (const float*)d_in[6];
  const float* mlpb  = (const float*)d_in[7];
  const float* gamma = (const float*)d_in[8];
  const float* beta  = (const float*)d_in[9];
  const float* wraw  = (const float*)d_in[10];
  float* out = (float*)d_out;

  // workspace carve (256B aligned slots)
  char* w = (char*)d_ws;
  size_t off = 0;
  auto take = [&](size_t bytes) -> void* {
    void* p = w + off;
    off = (off + bytes + 255) & ~(size_t)255;
    return p;
  };
  unsigned* deg    = (unsigned*)take((size_t)NN * 4);
  float*    dis    = (float*)take((size_t)NN * 4);
  unsigned* exc    = (unsigned*)take((size_t)NN * 4);
  unsigned* bsum   = (unsigned*)take((size_t)NB * 4);
  unsigned* boff   = (unsigned*)take((size_t)NB * 4);
  int*      rowptr = (int*)take((size_t)(NN + 1) * 4);
  int*      cur    = (int*)take((size_t)NN * 4);
  int*      perm   = (int*)take((size_t)EE * 4);
  float*    xw1s   = (float*)take((size_t)NN * HIDN * 4);
  float*    rh1s   = (float*)take((size_t)NN * HIDN * 4);
  float*    agg2   = (float*)take((size_t)NN * HIDN * 4);
  double*   gsum   = (double*)take(CCH * 8);
  double*   gsq    = (double*)take(CCH * 8);
  float*    bnp    = (float*)take(3 * CCH * 4);
  (void)ws_size; (void)n_in; (void)in_sizes; (void)out_size;

  hipMemsetAsync(deg, 0, (size_t)NN * 4, stream);
  hipMemsetAsync(gsum, 0, CCH * 8, stream);
  hipMemsetAsync(gsq, 0, CCH * 8, stream);

  // CSR build: XCD-partitioned histogram -> scan -> XCD-partitioned place
  k_hist<<<2048, 256, 0, stream>>>(ei, deg);
  k_scan_part<<<NB, 256, 0, stream>>>(deg, exc, bsum);
  k_scan_boff<<<1, 512, 0, stream>>>(bsum, boff);
  k_scan_final<<<(NN + 256) / 256 + 1, 256, 0, stream>>>(exc, boff, deg, rowptr, cur, dis);
  k_place<<<2048, 256, 0, stream>>>(ei, cur, perm);

  // dense transform (pad-17 conflict-free LDS) + 2 agg passes + tail
  k_gemm1<<<(NN + G1_ROWS_PER_BLOCK - 1) / G1_ROWS_PER_BLOCK, 256, 0, stream>>>(
      x, w1, dis, xw1s);
  k_agg<0><<<(NN + 3) / 4, 256, 0, stream>>>(rowptr, perm, dis, xw1s, b1, rh1s);
  k_agg<1><<<(NN + 3) / 4, 256, 0, stream>>>(rowptr, perm, dis, rh1s, b1, agg2);
  k_fuse2<<<4096, 256, 0, stream>>>(agg2, w2, b2, mlpw, mlpb, wraw, out, gsum, gsq);
  k_stats<<<1, 64, 0, stream>>>(gsum, gsq, gamma, beta, bnp);
  k_out<<<2048, 256, 0, stream>>>(out, bnp);
}

// Round 10
// 606.862 us; speedup vs baseline: 1.0255x; 1.0210x over previous
//
#include <hip/hip_runtime.h>
#include <math.h>

// Problem constants (fixed by the reference)
#define NN   100000
#define FIN  1024
#define HIDN 16
#define CCH  64
#define EE   3200000
#define BNEPS 1e-5f
#define NB   ((NN + 255) / 256)   // 391 scan blocks
#define NPART 8                   // XCD count
#define PSZ  (NN / NPART)         // 12500 nodes per partition

// ---------------------------------------------------------------------------
// k_hist: XCD-partitioned in-degree histogram (atomics stay in one XCD's L2)
// ---------------------------------------------------------------------------
__global__ __launch_bounds__(256) void k_hist(const int* __restrict__ ei,
                                              unsigned* __restrict__ deg) {
  int p = blockIdx.x & 7;
  int blk = blockIdx.x >> 3;
  int nblk = gridDim.x >> 3;
  int lo = p * PSZ, hi = lo + PSZ;
  for (int e = blk * 256 + threadIdx.x; e < EE; e += nblk * 256) {
    int d = ei[EE + e];
    if (d >= lo && d < hi) atomicAdd(&deg[d], 1u);
  }
}

// ---------------------------------------------------------------------------
// exclusive scan of deg -> rowptr (+ cur copy, + dis = rsqrt(deg+1))
// ---------------------------------------------------------------------------
__global__ __launch_bounds__(256) void k_scan_part(const unsigned* __restrict__ deg,
                                                   unsigned* __restrict__ exc,
                                                   unsigned* __restrict__ bsum) {
  __shared__ unsigned s[256];
  int t = threadIdx.x, i = blockIdx.x * 256 + t;
  unsigned v = (i < NN) ? deg[i] : 0u;
  s[t] = v;
  __syncthreads();
#pragma unroll
  for (int off = 1; off < 256; off <<= 1) {
    unsigned u = (t >= off) ? s[t - off] : 0u;
    __syncthreads();
    s[t] += u;
    __syncthreads();
  }
  if (i < NN) exc[i] = s[t] - v;
  if (t == 255) bsum[blockIdx.x] = s[255];
}

__global__ __launch_bounds__(512) void k_scan_boff(const unsigned* __restrict__ bsum,
                                                   unsigned* __restrict__ boff) {
  __shared__ unsigned s[512];
  int t = threadIdx.x;
  unsigned v = (t < NB) ? bsum[t] : 0u;
  s[t] = v;
  __syncthreads();
#pragma unroll
  for (int off = 1; off < 512; off <<= 1) {
    unsigned u = (t >= off) ? s[t - off] : 0u;
    __syncthreads();
    s[t] += u;
    __syncthreads();
  }
  if (t < NB) boff[t] = s[t] - v;
}

__global__ __launch_bounds__(256) void k_scan_final(const unsigned* __restrict__ exc,
                                                    const unsigned* __restrict__ boff,
                                                    const unsigned* __restrict__ deg,
                                                    int* __restrict__ rowptr,
                                                    int* __restrict__ cur,
                                                    float* __restrict__ dis) {
  int i = blockIdx.x * 256 + threadIdx.x;
  if (i < NN) {
    int r = (int)(boff[i >> 8] + exc[i]);
    rowptr[i] = r;
    cur[i] = r;
    dis[i] = rsqrtf((float)(deg[i] + 1u));
  } else if (i == NN) {
    rowptr[NN] = EE;
  }
}

// ---------------------------------------------------------------------------
// k_place: XCD-partitioned bucket placement (cur + perm slices L2-local)
// ---------------------------------------------------------------------------
__global__ __launch_bounds__(256) void k_place(const int* __restrict__ ei,
                                               int* __restrict__ cur,
                                               int* __restrict__ perm) {
  int p = blockIdx.x & 7;
  int blk = blockIdx.x >> 3;
  int nblk = gridDim.x >> 3;
  int lo = p * PSZ, hi = lo + PSZ;
  for (int e = blk * 256 + threadIdx.x; e < EE; e += nblk * 256) {
    int d = ei[EE + e];
    if (d >= lo && d < hi) {
      int s = ei[e];
      int slot = atomicAdd(&cur[d], 1);
      perm[slot] = s;
    }
  }
}

// ---------------------------------------------------------------------------
// k_gemm1: xw1s[N,16] = (x[N,1024] @ w1[1024,16]) * dis_i  (pre-scaled)
// ROUND-7 EXACT (593us config): single buffer, all 64 x-loads prefetched
// nontemporal, w1 in LDS 64KB quad-swizzled ((lane>>1)&3 is conflict-free
// for the 8-lane b128 phases; r8/r9's "fix" chased the butterfly's bpermute
// counts, not a real read conflict). (256,2): no spill.
// ---------------------------------------------------------------------------
#define G1_ROWS_PER_BLOCK 128   // 4 waves * 32 rows
__global__ __launch_bounds__(256, 2) void k_gemm1(const float* __restrict__ x,
                                                  const float* __restrict__ w1,
                                                  const float* __restrict__ dis,
                                                  float* __restrict__ xw1s) {
  __shared__ __align__(16) float w1s[1024 * 16];
  const float4* w1v = (const float4*)w1;
  for (int idx = threadIdx.x; idx < 4096; idx += 256) {
    int k = idx >> 2, qj = idx & 3;
    int pq = qj ^ ((k >> 1) & 3);               // quad swizzle
    *(float4*)&w1s[(k << 4) + (pq << 2)] = w1v[idx];
  }
  __syncthreads();

  const int lane = threadIdx.x & 63;
  const int wave = threadIdx.x >> 6;
  const int sw = (lane >> 1) & 3;
  const int wave_row0 = blockIdx.x * G1_ROWS_PER_BLOCK + wave * 32;

  for (int g = 0; g < 8; ++g) {
    int row0 = wave_row0 + g * 4;
    if (row0 >= NN) break;
    int r0 = row0;
    int r1 = min(row0 + 1, NN - 1);
    int r2 = min(row0 + 2, NN - 1);
    int r3 = min(row0 + 3, NN - 1);

    const float* p0 = x + (size_t)r0 * FIN + lane;
    const float* p1 = x + (size_t)r1 * FIN + lane;
    const float* p2 = x + (size_t)r2 * FIN + lane;
    const float* p3 = x + (size_t)r3 * FIN + lane;

    float xa[16], xb[16], xc[16], xd[16];
#pragma unroll
    for (int i = 0; i < 16; ++i) {
      xa[i] = __builtin_nontemporal_load(p0 + i * 64);
      xb[i] = __builtin_nontemporal_load(p1 + i * 64);
      xc[i] = __builtin_nontemporal_load(p2 + i * 64);
      xd[i] = __builtin_nontemporal_load(p3 + i * 64);
    }

    float acc[64];
#pragma unroll
    for (int t = 0; t < 64; ++t) acc[t] = 0.0f;

#pragma unroll
    for (int i = 0; i < 16; ++i) {
      const float* wr = &w1s[(i * 64 + lane) << 4];
      float xv0 = xa[i], xv1 = xb[i], xv2 = xc[i], xv3 = xd[i];
#pragma unroll
      for (int q = 0; q < 4; ++q) {
        float4 wq = *(const float4*)(wr + ((q ^ sw) << 2));
        int b = q * 4;
        acc[b + 0]      += xv0 * wq.x;
        acc[b + 1]      += xv0 * wq.y;
        acc[b + 2]      += xv0 * wq.z;
        acc[b + 3]      += xv0 * wq.w;
        acc[16 + b + 0] += xv1 * wq.x;
        acc[16 + b + 1] += xv1 * wq.y;
        acc[16 + b + 2] += xv1 * wq.z;
        acc[16 + b + 3] += xv1 * wq.w;
        acc[32 + b + 0] += xv2 * wq.x;
        acc[32 + b + 1] += xv2 * wq.y;
        acc[32 + b + 2] += xv2 * wq.z;
        acc[32 + b + 3] += xv2 * wq.w;
        acc[48 + b + 0] += xv3 * wq.x;
        acc[48 + b + 1] += xv3 * wq.y;
        acc[48 + b + 2] += xv3 * wq.z;
        acc[48 + b + 3] += xv3 * wq.w;
      }
    }

    // butterfly transpose-reduce: lane l ends with (row l>>4, col l&15)
#pragma unroll
    for (int o = 32; o >= 1; o >>= 1) {
      bool up = (lane & o) != 0;
#pragma unroll
      for (int t = 0; t < o; ++t) {
        float send = up ? acc[t] : acc[t + o];
        float recv = __shfl_xor(send, o, 64);
        float keep = up ? acc[t + o] : acc[t];
        acc[t] = keep + recv;
      }
    }

    int grow = row0 + (lane >> 4);
    if (grow < NN) xw1s[grow * HIDN + (lane & 15)] = acc[0] * dis[grow];
  }
}

// ---------------------------------------------------------------------------
// k_agg1: CSR gather-reduce layer 1, ONE WAVE PER NODE, unroll-2 (r7 exact).
//   out = relu(dis_i*(sum_e sfs[perm[e]] + sfs[i]) + b1[j]) * dis_i
// ---------------------------------------------------------------------------
__global__ __launch_bounds__(256) void k_agg1(const int* __restrict__ rowptr,
                                              const int* __restrict__ perm,
                                              const float* __restrict__ dis,
                                              const float* __restrict__ sfs,
                                              const float* __restrict__ b1,
                                              float* __restrict__ out) {
  int g = blockIdx.x * 4 + (threadIdx.x >> 6);     // node (wave id)
  if (g >= NN) return;
  int lane = threadIdx.x & 63;
  int eo = lane >> 4;                              // 0..3
  int j = lane & 15;                               // channel
  int beg = rowptr[g], end = rowptr[g + 1];
  float acc0 = 0.0f, acc1 = 0.0f;
  int e = beg + eo;
  for (; e + 4 < end; e += 8) {
    int s0 = perm[e];
    int s1 = perm[e + 4];
    acc0 += sfs[(size_t)s0 * HIDN + j];
    acc1 += sfs[(size_t)s1 * HIDN + j];
  }
  if (e < end) acc0 += sfs[(size_t)perm[e] * HIDN + j];
  float acc = acc0 + acc1;
  acc += __shfl_xor(acc, 16, 64);
  acc += __shfl_xor(acc, 32, 64);
  if (eo == 0) {
    float di = dis[g];
    float v = di * (acc + sfs[(size_t)g * HIDN + j]);
    out[(size_t)g * HIDN + j] = fmaxf(v + b1[j], 0.0f) * di;
  }
}

// ---------------------------------------------------------------------------
// k_aggfuse: layer-2 aggregation + full tail, ONE WAVE PER NODE (25000
// blocks -> 100K independent waves; round-4's fusion failed at 2048 blocks
// x 12-node serial chains). Tail VALU chain hides in the gather's latency
// shadow. NO BN stats here (moved to k_bnstats; keeps the chain short and
// avoids the atomic flood).
// ---------------------------------------------------------------------------
__global__ __launch_bounds__(256) void k_aggfuse(const int* __restrict__ rowptr,
                                                 const int* __restrict__ perm,
                                                 const float* __restrict__ dis,
                                                 const float* __restrict__ sfs,
                                                 const float* __restrict__ w2,
                                                 const float* __restrict__ b2,
                                                 const float* __restrict__ mlpw,
                                                 const float* __restrict__ mlpb,
                                                 const float* __restrict__ wraw,
                                                 float* __restrict__ out) {
  __shared__ __align__(16) float2 w2p[8 * CCH];     // (w2[2k][j], w2[2k+1][j])
  __shared__ __align__(16) float2 mlpp[32 * CCH];   // (mlp[2c][j], mlp[2c+1][j])
  __shared__ __align__(16) float avbuf[4][HIDN];
  __shared__ __align__(16) float gbuf[4][CCH];
  for (int idx = threadIdx.x; idx < 8 * CCH; idx += 256) {
    int k2 = idx >> 6, j = idx & 63;
    w2p[idx] = make_float2(w2[(2 * k2) * CCH + j], w2[(2 * k2 + 1) * CCH + j]);
  }
  for (int idx = threadIdx.x; idx < 32 * CCH; idx += 256) {
    int c2 = idx >> 6, j = idx & 63;
    mlpp[idx] = make_float2(mlpw[(2 * c2) * CCH + j], mlpw[(2 * c2 + 1) * CCH + j]);
  }
  __syncthreads();

  const int g = blockIdx.x * 4 + (threadIdx.x >> 6);   // node (wave id)
  if (g >= NN) return;
  const int lane = threadIdx.x & 63;
  const int wave = threadIdx.x >> 6;
  const int eo = lane >> 4;
  const int jc = lane & 15;      // agg channel
  const int j = lane;            // tail channel 0..63

  // ---- layer-2 aggregation (features pre-scaled by dis[src]) ----
  int beg = rowptr[g], end = rowptr[g + 1];
  float acc0 = 0.0f, acc1 = 0.0f;
  int e = beg + eo;
  for (; e + 4 < end; e += 8) {
    int s0 = perm[e];
    int s1 = perm[e + 4];
    acc0 += sfs[(size_t)s0 * HIDN + jc];
    acc1 += sfs[(size_t)s1 * HIDN + jc];
  }
  if (e < end) acc0 += sfs[(size_t)perm[e] * HIDN + jc];
  float acc = acc0 + acc1;
  acc += __shfl_xor(acc, 16, 64);
  acc += __shfl_xor(acc, 32, 64);
  float di = dis[g];
  float av = di * (acc + sfs[(size_t)g * HIDN + jc]);  // valid in ALL lanes
  if (lane < HIDN) avbuf[wave][lane] = av;

  // ---- h2 = av @ w2 + b2 ----
  float2 h2p = make_float2(0.0f, 0.0f);
#pragma unroll
  for (int k2 = 0; k2 < 8; ++k2) {
    float2 a = *(const float2*)&avbuf[wave][2 * k2];   // broadcast read
    float2 wv = w2p[k2 * CCH + j];
    h2p.x = fmaf(a.x, wv.x, h2p.x);
    h2p.y = fmaf(a.y, wv.y, h2p.y);
  }
  float h2 = h2p.x + h2p.y + b2[j];

  // ---- log_softmax ----
  float mx = h2;
#pragma unroll
  for (int o = 32; o >= 1; o >>= 1) mx = fmaxf(mx, __shfl_xor(mx, o, 64));
  float ex = __expf(h2 - mx);
  float se = ex;
#pragma unroll
  for (int o = 32; o >= 1; o >>= 1) se += __shfl_xor(se, o, 64);
  float lsm = h2 - mx - __logf(se);

  // ---- channel weight + MLP ----
  float gg = __expf(wraw[g]) * lsm;
  gbuf[wave][j] = gg;

  float2 mp = make_float2(0.0f, 0.0f);
#pragma unroll
  for (int c2 = 0; c2 < 32; ++c2) {
    float2 gv = *(const float2*)&gbuf[wave][2 * c2];   // broadcast read
    float2 wv = mlpp[c2 * CCH + j];
    mp.x = fmaf(gv.x, wv.x, mp.x);
    mp.y = fmaf(gv.y, wv.y, mp.y);
  }
  out[(size_t)g * CCH + j] = mp.x + mp.y + mlpb[j];
}

// ---------------------------------------------------------------------------
// k_bnstats: streaming f64 sum/sumsq over out (coalesced; 256 blocks ->
// only 256 atomics per channel address)
// ---------------------------------------------------------------------------
__global__ __launch_bounds__(256) void k_bnstats(const float* __restrict__ out,
                                                 double* __restrict__ gsum,
                                                 double* __restrict__ gsq) {
  __shared__ double reds[256];
  __shared__ double redq[256];
  const int lane = threadIdx.x & 63;
  const int wave = threadIdx.x >> 6;
  double s = 0.0, q = 0.0;
  for (int i = blockIdx.x * 4 + wave; i < NN; i += gridDim.x * 4) {
    float m = out[(size_t)i * CCH + lane];
    s += (double)m;
    q = fma((double)m, (double)m, q);
  }
  reds[threadIdx.x] = s;
  redq[threadIdx.x] = q;
  __syncthreads();
  if (threadIdx.x < 64) {
    double ss = reds[threadIdx.x] + reds[threadIdx.x + 64] +
                reds[threadIdx.x + 128] + reds[threadIdx.x + 192];
    double qq = redq[threadIdx.x] + redq[threadIdx.x + 64] +
                redq[threadIdx.x + 128] + redq[threadIdx.x + 192];
    atomicAdd(&gsum[threadIdx.x], ss);
    atomicAdd(&gsq[threadIdx.x], qq);
  }
}

// ---------------------------------------------------------------------------
// k_stats: finalize BN params in double (no cancellation)
// ---------------------------------------------------------------------------
__global__ void k_stats(const double* __restrict__ gsum,
                        const double* __restrict__ gsq,
                        const float* __restrict__ gamma,
                        const float* __restrict__ beta,
                        float* __restrict__ bnp) {
  int j = threadIdx.x;
  if (j >= CCH) return;
  const double inv_n = 1.0 / (double)NN;
  double mean = gsum[j] * inv_n;
  double var = gsq[j] * inv_n - mean * mean;
  float sc = (float)(rsqrt(var + (double)BNEPS)) * gamma[j];
  bnp[j] = (float)mean;
  bnp[CCH + j] = sc;
  bnp[2 * CCH + j] = beta[j];
}

// ---------------------------------------------------------------------------
// k_out: BN apply + final log_softmax, in-place on d_out (wave per row)
// ---------------------------------------------------------------------------
__global__ __launch_bounds__(256) void k_out(float* __restrict__ out,
                                             const float* __restrict__ bnp) {
  const int lane = threadIdx.x & 63;
  const int wave = threadIdx.x >> 6;
  const int j = lane;
  const float mean = bnp[j];
  const float sc = bnp[CCH + j];
  const float bt = bnp[2 * CCH + j];
  const int gw = blockIdx.x * 4 + wave;
  const int nw = gridDim.x * 4;
  for (int i = gw; i < NN; i += nw) {
    float m = out[(size_t)i * CCH + j];
    float y = fmaf(m - mean, sc, bt);
    float mx = y;
#pragma unroll
    for (int o = 32; o >= 1; o >>= 1) mx = fmaxf(mx, __shfl_xor(mx, o, 64));
    float ex = __expf(y - mx);
    float se = ex;
#pragma unroll
    for (int o = 32; o >= 1; o >>= 1) se += __shfl_xor(se, o, 64);
    out[(size_t)i * CCH + j] = y - mx - __logf(se);
  }
}

// ---------------------------------------------------------------------------
extern "C" void kernel_launch(void* const* d_in, const int* in_sizes, int n_in,
                              void* d_out, int out_size, void* d_ws, size_t ws_size,
                              hipStream_t stream) {
  const float* x     = (const float*)d_in[0];
  const int*   ei    = (const int*)d_in[1];
  const float* w1    = (const float*)d_in[2];
  const float* b1    = (const float*)d_in[3];
  const float* w2    = (const float*)d_in[4];
  const float* b2    = (const float*)d_in[5];
  const float* mlpw  = (const float*)d_in[6];
  const float* mlpb  = (const float*)d_in[7];
  const float* gamma = (const float*)d_in[8];
  const float* beta  = (const float*)d_in[9];
  const float* wraw  = (const float*)d_in[10];
  float* out = (float*)d_out;

  // workspace carve (256B aligned slots)
  char* w = (char*)d_ws;
  size_t off = 0;
  auto take = [&](size_t bytes) -> void* {
    void* p = w + off;
    off = (off + bytes + 255) & ~(size_t)255;
    return p;
  };
  unsigned* deg    = (unsigned*)take((size_t)NN * 4);
  float*    dis    = (float*)take((size_t)NN * 4);
  unsigned* exc    = (unsigned*)take((size_t)NN * 4);
  unsigned* bsum   = (unsigned*)take((size_t)NB * 4);
  unsigned* boff   = (unsigned*)take((size_t)NB * 4);
  int*      rowptr = (int*)take((size_t)(NN + 1) * 4);
  int*      cur    = (int*)take((size_t)NN * 4);
  int*      perm   = (int*)take((size_t)EE * 4);
  float*    xw1s   = (float*)take((size_t)NN * HIDN * 4);
  float*    rh1s   = (float*)take((size_t)NN * HIDN * 4);
  double*   gsum   = (double*)take(CCH * 8);
  double*   gsq    = (double*)take(CCH * 8);
  float*    bnp    = (float*)take(3 * CCH * 4);
  (void)ws_size; (void)n_in; (void)in_sizes; (void)out_size;

  hipMemsetAsync(deg, 0, (size_t)NN * 4, stream);
  hipMemsetAsync(gsum, 0, CCH * 8, stream);
  hipMemsetAsync(gsq, 0, CCH * 8, stream);

  // CSR build: XCD-partitioned histogram -> scan -> XCD-partitioned place
  k_hist<<<2048, 256, 0, stream>>>(ei, deg);
  k_scan_part<<<NB, 256, 0, stream>>>(deg, exc, bsum);
  k_scan_boff<<<1, 512, 0, stream>>>(bsum, boff);
  k_scan_final<<<(NN + 256) / 256 + 1, 256, 0, stream>>>(exc, boff, deg, rowptr, cur, dis);
  k_place<<<2048, 256, 0, stream>>>(ei, cur, perm);

  // dense transform + layer-1 agg + fused layer-2 agg/tail
  k_gemm1<<<(NN + G1_ROWS_PER_BLOCK - 1) / G1_ROWS_PER_BLOCK, 256, 0, stream>>>(
      x, w1, dis, xw1s);
  k_agg1<<<(NN + 3) / 4, 256, 0, stream>>>(rowptr, perm, dis, xw1s, b1, rh1s);
  k_aggfuse<<<(NN + 3) / 4, 256, 0, stream>>>(rowptr, perm, dis, rh1s, w2, b2,
                                              mlpw, mlpb, wraw, out);

  // BN stats + finalize + apply
  k_bnstats<<<256, 256, 0, stream>>>(out, gsum, gsq);
  k_stats<<<1, 64, 0, stream>>>(gsum, gsq, gamma, beta, bnp);
  k_out<<<1024, 256, 0, stream>>>(out, bnp);
}